// Round 18
// baseline (594.557 us; speedup 1.0000x reference)
//
#include <hip/hip_runtime.h>
#include <hip/hip_bf16.h>
#include <stdint.h>

#define Bb 128
#define Tt 256
#define Ee 300
#define EP 320
#define Hh 256
#define G4 1024
#define NTAG 9

typedef __bf16 bf16x8 __attribute__((ext_vector_type(8)));
typedef float f32x4 __attribute__((ext_vector_type(4)));
typedef float f32x2 __attribute__((ext_vector_type(2)));
typedef int i32x8 __attribute__((ext_vector_type(8)));
typedef unsigned short u16;
typedef unsigned int u32;
typedef unsigned char u8;
typedef long i64;

union U4B { uint4 q; bf16x8 v; };

static __device__ __forceinline__ float bf2f(u32 u){
  union { float f; u32 u; } w; w.u = u << 16; return w.f;
}
static __device__ __forceinline__ u16 f2bf(float f){
  union { float f; u32 u; } w; w.f = f;
  u32 x = w.u;
  return (u16)((x + 0x7fffu + ((x >> 16) & 1u)) >> 16);
}
// permuted (dir-local) column -> original gate column. Permutation: wave w
// (c>>7) owns hidden units [32w,32w+32); within its 128 cols: 4 gates x 32.
static __device__ __forceinline__ int perm2orig(int c){
  int w = c >> 7, r = c & 127, g = r >> 5, jj = r & 31;
  return g * 256 + w * 32 + jj;
}
static __device__ __forceinline__ float frcp(float x){ return __builtin_amdgcn_rcpf(x); }
static __device__ __forceinline__ float fexp2(float x){
  float r; asm("v_exp_f32 %0, %1" : "=v"(r) : "v"(x)); return r;
}
static __device__ __forceinline__ f32x2 vexp2(f32x2 x){
  f32x2 r; r[0] = fexp2(x[0]); r[1] = fexp2(x[1]); return r;
}
static __device__ __forceinline__ f32x2 vrcp(f32x2 x){
  f32x2 r; r[0] = frcp(x[0]); r[1] = frcp(x[1]); return r;
}
static __device__ __forceinline__ f32x2 vfabs(f32x2 x){
  f32x2 r; r[0] = __builtin_fabsf(x[0]); r[1] = __builtin_fabsf(x[1]); return r;
}
static __device__ __forceinline__ f32x2 vminc(f32x2 x, float c){
  f32x2 r; r[0] = fminf(x[0], c); r[1] = fminf(x[1], c); return r;
}
static __device__ __forceinline__ f32x2 vcps(f32x2 m, f32x2 s){
  f32x2 r; r[0] = __builtin_copysignf(m[0], s[0]);
  r[1] = __builtin_copysignf(m[1], s[1]); return r;
}
static __device__ __forceinline__ void gl_lds16(const void* g, void* l){
  __builtin_amdgcn_global_load_lds((const __attribute__((address_space(1))) u32*)(g),
                                   (__attribute__((address_space(3))) u32*)(l), 16, 0, 0);
}

// ---------------- fused prep + gather ----------------------------------------
// blocks [0,320) W | [320,384) U | [384,392) b | [392,396) fcW | [396,...) gather
__global__ void prep_k(const float* __restrict__ Wf, const float* __restrict__ Wb,
                       const float* __restrict__ Uf, const float* __restrict__ Ub,
                       const float* __restrict__ bf_, const float* __restrict__ bb_,
                       const float* __restrict__ fcW, const int* __restrict__ inp,
                       const float* __restrict__ emb,
                       u16* __restrict__ Wpk, u8* __restrict__ Upk8,
                       float* __restrict__ bperm, u8* __restrict__ fcw8,
                       u16* __restrict__ xbf){
  int blk = blockIdx.x;
  if(blk < 320){
    int idx = blk * 256 + threadIdx.x;
    if(idx >= 128 * 10 * 64) return;
    int lane = idx & 63;
    int kk = (idx >> 6) % 10;
    int nt2 = idx / 640;
    int d = nt2 >> 6, ntd = nt2 & 63;
    int oc = perm2orig(ntd * 16 + (lane & 15));
    const float* W = d ? Wb : Wf;
    int k0 = kk * 32 + ((lane >> 4) << 3);
    u16 o[8];
    #pragma unroll
    for(int j = 0; j < 8; ++j){
      int k = k0 + j;
      o[j] = (k < Ee) ? f2bf(W[(size_t)k * G4 + oc]) : (u16)0;
    }
    uint4 q;
    q.x = o[0] | ((u32)o[1] << 16); q.y = o[2] | ((u32)o[3] << 16);
    q.z = o[4] | ((u32)o[5] << 16); q.w = o[6] | ((u32)o[7] << 16);
    *(uint4*)(Wpk + (size_t)idx * 8) = q;
  } else if(blk < 384){
    int idx = (blk - 320) * 256 + threadIdx.x;
    if(idx >= 2 * 64 * 2 * 64) return;
    int lane = idx & 63;
    int kh = (idx >> 6) & 1;
    int nt = (idx >> 7) & 63;
    int d = idx >> 13;
    int oc = perm2orig(nt * 16 + (lane & 15));
    const float* U = d ? Ub : Uf;
    int k0 = kh * 128 + (lane >> 4) * 32;
    u32 o[8];
    #pragma unroll
    for(int m = 0; m < 8; ++m){
      float v0 = U[(size_t)(k0 + 4 * m + 0) * G4 + oc] * 32.f;
      float v1 = U[(size_t)(k0 + 4 * m + 1) * G4 + oc] * 32.f;
      float v2 = U[(size_t)(k0 + 4 * m + 2) * G4 + oc] * 32.f;
      float v3 = U[(size_t)(k0 + 4 * m + 3) * G4 + oc] * 32.f;
      int pk = __builtin_amdgcn_cvt_pk_fp8_f32(v0, v1, 0, false);
      pk = __builtin_amdgcn_cvt_pk_fp8_f32(v2, v3, pk, true);
      o[m] = (u32)pk;
    }
    uint4* dst = (uint4*)(Upk8 + (size_t)idx * 32);
    dst[0] = (uint4){o[0], o[1], o[2], o[3]};
    dst[1] = (uint4){o[4], o[5], o[6], o[7]};
  } else if(blk < 392){
    int c = (blk - 384) * 256 + threadIdx.x;
    if(c >= 2048) return;
    const float* src = (c >> 10) ? bb_ : bf_;
    bperm[c] = src[perm2orig(c & 1023)];
  } else if(blk < 396){
    int idx = (blk - 392) * 256 + threadIdx.x;
    if(idx >= 1024) return;
    int lane = idx & 63, kk = idx >> 6;
    int col = lane & 15;
    int k0 = kk * 32 + ((lane >> 4) << 3);
    float v[8];
    #pragma unroll
    for(int j = 0; j < 8; ++j)
      v[j] = (col < NTAG) ? fcW[(size_t)(k0 + j) * NTAG + col] * 256.f : 0.f;
    int lo = __builtin_amdgcn_cvt_pk_fp8_f32(v[0], v[1], 0, false);
    lo = __builtin_amdgcn_cvt_pk_fp8_f32(v[2], v[3], lo, true);
    int hi = __builtin_amdgcn_cvt_pk_fp8_f32(v[4], v[5], 0, false);
    hi = __builtin_amdgcn_cvt_pk_fp8_f32(v[6], v[7], hi, true);
    uint2 q; q.x = (u32)lo; q.y = (u32)hi;
    *(uint2*)(fcw8 + (size_t)idx * 8) = q;
  } else {
    // gather: 2 rows per block; emb rows 16B-aligned (1200B stride)
    int row = (blk - 396) * 2 + (threadIdx.x >> 7);
    int j = threadIdx.x & 127;
    int t = row >> 7, b = row & 127;
    int tok = inp[b * Tt + t];
    u16* dst = xbf + (size_t)row * EP;
    if(j < 75){
      float4 v = *(const float4*)(emb + (size_t)tok * Ee + j * 4);
      u32 lo = f2bf(v.x) | ((u32)f2bf(v.y) << 16);
      u32 hi = f2bf(v.z) | ((u32)f2bf(v.w) << 16);
      *(uint2*)(dst + j * 4) = (uint2){lo, hi};
    } else if(j < 80){
      *(uint2*)(dst + j * 4) = (uint2){0u, 0u};
    }
  }
}

// ---------------- xW GEMM: 2 t-tiles per WG, B-frags reused ------------------
__global__ __launch_bounds__(256, 2) void xw_gemm_k(const u16* __restrict__ xbf,
    const u16* __restrict__ Wpk, const float* __restrict__ bperm,
    u16* __restrict__ xwpk){
  __shared__ uint4 At[2][512];       // 2 tiles x 128 rows x 64B, XOR-swizzled
  int t0 = blockIdx.y * 2, nblk = blockIdx.x;
  int tid = threadIdx.x, lane = tid & 63, w = tid >> 6;
  int mh = w >> 1, nh = w & 1;
  f32x4 acc[2][4][4];
  #pragma unroll
  for(int tt = 0; tt < 2; ++tt)
    #pragma unroll
    for(int i = 0; i < 4; ++i)
      #pragma unroll
      for(int j = 0; j < 4; ++j) acc[tt][i][j] = (f32x4){0.f, 0.f, 0.f, 0.f};
  for(int ks = 0; ks < 10; ++ks){
    __syncthreads();
    #pragma unroll
    for(int it = 0; it < 2; ++it){
      int row = it * 64 + w * 16 + (lane >> 2);
      int seg = (lane & 3) ^ (row & 3);
      gl_lds16(xbf + (size_t)(t0 * 128 + row) * EP + ks * 32 + seg * 8,
               &At[0][it * 256 + w * 64]);
      gl_lds16(xbf + (size_t)((t0 + 1) * 128 + row) * EP + ks * 32 + seg * 8,
               &At[1][it * 256 + w * 64]);
    }
    asm volatile("s_waitcnt vmcnt(0)" ::: "memory");
    __syncthreads();
    U4B bv[4];
    #pragma unroll
    for(int n = 0; n < 4; ++n){
      int ntg = nblk * 8 + nh * 4 + n;
      bv[n].q = *(const uint4*)(Wpk + ((size_t)(ntg * 10 + ks) * 64 + lane) * 8);
    }
    #pragma unroll
    for(int tt = 0; tt < 2; ++tt){
      U4B a[4];
      #pragma unroll
      for(int m = 0; m < 4; ++m){
        int row = (mh * 4 + m) * 16 + (lane & 15);
        a[m].q = At[tt][row * 4 + ((lane >> 4) ^ (row & 3))];
      }
      #pragma unroll
      for(int m = 0; m < 4; ++m)
        #pragma unroll
        for(int n = 0; n < 4; ++n)
          acc[tt][m][n] = __builtin_amdgcn_mfma_f32_16x16x32_bf16(a[m].v, bv[n].v, acc[tt][m][n], 0, 0, 0);
    }
  }
  #pragma unroll
  for(int tt = 0; tt < 2; ++tt){
    int t = t0 + tt;
    #pragma unroll
    for(int m = 0; m < 4; ++m){
      int grp = mh * 4 + m;
      #pragma unroll
      for(int n = 0; n < 4; ++n){
        int ntg = nblk * 8 + nh * 4 + n;
        int d = ntg >> 6, nd = ntg & 63;
        float bias = bperm[ntg * 16 + (lane & 15)];
        u16 h0 = f2bf((acc[tt][m][n][0] + bias) * 512.f), h1 = f2bf((acc[tt][m][n][1] + bias) * 512.f);
        u16 h2 = f2bf((acc[tt][m][n][2] + bias) * 512.f), h3 = f2bf((acc[tt][m][n][3] + bias) * 512.f);
        uint2 p; p.x = h0 | ((u32)h1 << 16); p.y = h2 | ((u32)h3 << 16);
        *(uint2*)(xwpk + ((((size_t)(d * 8 + grp) * Tt + t) * 64 + nd) * 64 + lane) * 4) = p;
      }
    }
  }
}

// ---------------- LSTM recurrence (R12 numerics; xW via register dbuf) -------
// 16 WGs x 512 thr (8 waves = 2/SIMD). U fp8 AGPR-pinned K=128 B-frags;
// v_mfma_f32_16x16x128_f8f6f4. Hf8 dbuf, ONE barrier/step. xW(t+1) prefetched
// into registers (8 x global_load_dwordx2, pinned before MFMAs by
// sched_barrier); consumed next step with compiler-managed waitcnt. Loop
// unrolled x2 to double-buffer the prefetch registers without copies.
__global__ __launch_bounds__(512, 2) void lstm_rec_k(const u16* __restrict__ xwpk,
    const u8* __restrict__ Upk8, u8* __restrict__ hseq8){
  __shared__ u32 Hf8[2][1024];       // 8KB fp8 h transposed dbuf [unit*16+row]
  int bid = blockIdx.x;
  int d = bid >> 3, grp = bid & 7;
  int tid = threadIdx.x, lane = tid & 63, w = tid >> 6;   // w: 0..7
  int arow = lane & 15, r4 = lane >> 4;

  // preload U slice into K=128 B-fragments (fp8, 8nt x 2kh x 8 regs = 128),
  // pinned into AGPRs (no remat; MFMA reads B from AGPR natively)
  i32x8 Ureg[8][2];
  const u8* Ub8 = Upk8 + (size_t)d * 262144;
  #pragma unroll
  for(int n = 0; n < 8; ++n)
    #pragma unroll
    for(int kh = 0; kh < 2; ++kh)
      Ureg[n][kh] = *(const i32x8*)(Ub8 + (((size_t)(w * 8 + n) * 2 + kh) * 64 + lane) * 32);
  #pragma unroll
  for(int n = 0; n < 8; ++n)
    #pragma unroll
    for(int kh = 0; kh < 2; ++kh)
      asm volatile("" : "+a"(Ureg[n][kh]));

  Hf8[0][tid] = 0u; Hf8[0][tid + 512] = 0u;
  f32x2 cst2[2][2];
  #pragma unroll
  for(int a = 0; a < 2; ++a)
    #pragma unroll
    for(int p = 0; p < 2; ++p) cst2[a][p] = (f32x2){0.f, 0.f};
  const u16* xwb = xwpk + (size_t)(d * 8 + grp) * Tt * 16384;
  u8* hs_base = hseq8 + (size_t)(d * 8 + grp) * Tt * 4096;
  u32 hf8base = (u32)(uintptr_t)(&Hf8[0][0]);
  u32* hf8u = (u32*)(&Hf8[0][0]);

  const float c1s = -1.44269504f / 512.f;
  const f32x2 C1  = (f32x2){c1s, c1s};
  const f32x2 C2  = (f32x2){2.f * c1s, 2.f * c1s};
  const f32x2 C3  = (f32x2){-2.f * 1.44269504f, -2.f * 1.44269504f};
  const f32x2 ONE = (f32x2){1.f, 1.f};

  uint2 xva[8], xvb[8];
  // prologue: load xW(t0) into xva
  {
    int t0 = d ? (Tt - 1) : 0;
    const u16* xwt0 = xwb + (size_t)t0 * 16384;
    #pragma unroll
    for(int n = 0; n < 8; ++n)
      xva[n] = *(const uint2*)(xwt0 + ((size_t)(w * 8 + n) * 64 + lane) * 4);
  }
  __syncthreads();

  auto STEP = [&](int st, uint2* xvin, uint2* xvout){
    int t = d ? (Tt - 1 - st) : st;
    int p = st & 1, c_ = p ^ 1;
    // A-fragments of h_{t-1} (K=128 x2): 8 tr_b8 reads from Hf8[p]
    union AFU { i64 dd[4]; i32x8 v; };
    AFU af0, af1;
    u32 av = hf8base + (u32)(p * 4096) + (u32)(r4 * 512 + arow * 8);
    asm volatile("ds_read_b64_tr_b8 %0, %1"             : "=v"(af0.dd[0]) : "v"(av));
    asm volatile("ds_read_b64_tr_b8 %0, %1 offset:128"  : "=v"(af0.dd[1]) : "v"(av));
    asm volatile("ds_read_b64_tr_b8 %0, %1 offset:256"  : "=v"(af0.dd[2]) : "v"(av));
    asm volatile("ds_read_b64_tr_b8 %0, %1 offset:384"  : "=v"(af0.dd[3]) : "v"(av));
    asm volatile("ds_read_b64_tr_b8 %0, %1 offset:2048" : "=v"(af1.dd[0]) : "v"(av));
    asm volatile("ds_read_b64_tr_b8 %0, %1 offset:2176" : "=v"(af1.dd[1]) : "v"(av));
    asm volatile("ds_read_b64_tr_b8 %0, %1 offset:2304" : "=v"(af1.dd[2]) : "v"(av));
    asm volatile("ds_read_b64_tr_b8 %0, %1 offset:2432" : "=v"(af1.dd[3]) : "v"(av));
    asm volatile("s_waitcnt lgkmcnt(0)" ::: "memory");   // afr data ready
    __builtin_amdgcn_sched_barrier(0);                   // rule 18: no MFMA hoist
    // acc init = 512*(xW+b) from prefetched regs (compiler inserts vmcnt)
    f32x4 acc[8];
    #pragma unroll
    for(int n = 0; n < 8; ++n){
      acc[n][0] = bf2f(xvin[n].x & 0xffffu);
      acc[n][1] = bf2f(xvin[n].x >> 16);
      acc[n][2] = bf2f(xvin[n].y & 0xffffu);
      acc[n][3] = bf2f(xvin[n].y >> 16);
    }
    // prefetch xW for st+1 into xvout (pinned before MFMAs)
    {
      int stn = (st + 1 < Tt) ? st + 1 : st;
      int tn = d ? (Tt - 1 - stn) : stn;
      const u16* xwtn = xwb + (size_t)tn * 16384;
      #pragma unroll
      for(int n = 0; n < 8; ++n)
        xvout[n] = *(const uint2*)(xwtn + ((size_t)(w * 8 + n) * 64 + lane) * 4);
    }
    __builtin_amdgcn_sched_barrier(0);                   // loads issue pre-MFMA
    // 16 K=128 MFMAs (fp8xfp8 via f8f6f4 default formats)
    #pragma unroll
    for(int n = 0; n < 8; ++n){
      asm volatile("v_mfma_f32_16x16x128_f8f6f4 %0, %1, %2, %0"
                   : "+v"(acc[n]) : "v"(af0.v), "a"(Ureg[n][0]));
      asm volatile("v_mfma_f32_16x16x128_f8f6f4 %0, %1, %2, %0"
                   : "+v"(acc[n]) : "v"(af1.v), "a"(Ureg[n][1]));
    }
    // gates: n {0,1}=i, {2,3}=f, {4,5}=g, {6,7}=o ; z = acc/512 (R12-exact)
    #pragma unroll
    for(int n1 = 0; n1 < 2; ++n1){
      f32x2 h16[2];
      #pragma unroll
      for(int pq = 0; pq < 2; ++pq){
        f32x2 ai = (f32x2){acc[0 + n1][2 * pq], acc[0 + n1][2 * pq + 1]};
        f32x2 af = (f32x2){acc[2 + n1][2 * pq], acc[2 + n1][2 * pq + 1]};
        f32x2 ag = (f32x2){acc[4 + n1][2 * pq], acc[4 + n1][2 * pq + 1]};
        f32x2 ao = (f32x2){acc[6 + n1][2 * pq], acc[6 + n1][2 * pq + 1]};
        f32x2 ei = vexp2(ai * C1);
        f32x2 ef = vexp2(af * C1);
        f32x2 eo = vexp2(ao * C1);
        f32x2 eg = vexp2(vminc(vfabs(ag), 10240.f) * C2);
        f32x2 ig = vcps(ONE - eg, ag) * vrcp((ONE + ei) * (ONE + eg));
        f32x2 fs = vrcp(ONE + ef);
        f32x2 cc = fs * cst2[n1][pq] + ig;
        cst2[n1][pq] = cc;
        f32x2 ec = vexp2(vminc(vfabs(cc), 20.f) * C3);
        f32x2 hh = vcps(ONE - ec, cc) * vrcp((ONE + eo) * (ONE + ec));
        h16[pq] = hh * (f32x2){16.f, 16.f};
      }
      int pk = __builtin_amdgcn_cvt_pk_fp8_f32(h16[0][0], h16[0][1], 0, false);
      pk = __builtin_amdgcn_cvt_pk_fp8_f32(h16[1][0], h16[1][1], pk, true);
      int unit = w * 32 + n1 * 16 + arow;
      hf8u[c_ * 1024 + unit * 4 + r4] = (u32)pk;
      *(u32*)(hs_base + (size_t)t * 4096 + unit * 16 + r4 * 4) = (u32)pk;
    }
    asm volatile("s_waitcnt lgkmcnt(0)" ::: "memory");   // h_t LDS writes done
    __builtin_amdgcn_s_barrier();                        // the ONE barrier
  };

  for(int st = 0; st < Tt; st += 2){
    STEP(st, xva, xvb);
    STEP(st + 1, xvb, xva);
  }
}

// ---------------- logits: one wave per (grp,t), tr_b8 + fp8 MFMA -------------
__global__ __launch_bounds__(256) void logits_k(const u8* __restrict__ hseq8,
    const u8* __restrict__ fcw8, const float* __restrict__ fcb,
    float* __restrict__ out){
  __shared__ u8 Ht[4][8192];
  int widx = threadIdx.x >> 6, lane = threadIdx.x & 63;
  int wid = blockIdx.x * 4 + widx;
  int grp = wid >> 8, t = wid & 255;
  i64 bf[16];
  #pragma unroll
  for(int kk = 0; kk < 16; ++kk)
    bf[kk] = *(const i64*)(fcw8 + ((size_t)kk * 64 + lane) * 8);
  const u8* hf = hseq8 + ((size_t)(0 * 8 + grp) * Tt + t) * 4096;
  const u8* hb = hseq8 + ((size_t)(1 * 8 + grp) * Tt + t) * 4096;
  #pragma unroll
  for(int j = 0; j < 4; ++j){
    gl_lds16(hf + j * 1024 + lane * 16, &Ht[widx][j * 1024]);
    gl_lds16(hb + j * 1024 + lane * 16, &Ht[widx][4096 + j * 1024]);
  }
  asm volatile("s_waitcnt vmcnt(0)" ::: "memory");
  __builtin_amdgcn_sched_barrier(0);
  u32 base = (u32)(uintptr_t)(&Ht[widx][0]) + lane * 8;
  i64 afr[16];
  #pragma unroll
  for(int kk = 0; kk < 16; ++kk){
    u32 a = base + kk * 512;
    asm volatile("ds_read_b64_tr_b8 %0, %1" : "=v"(afr[kk]) : "v"(a));
  }
  asm volatile("s_waitcnt lgkmcnt(0)" ::: "memory");
  __builtin_amdgcn_sched_barrier(0);
  f32x4 acc = (f32x4){0.f, 0.f, 0.f, 0.f};
  #pragma unroll
  for(int kk = 0; kk < 16; ++kk)
    acc = __builtin_amdgcn_mfma_f32_16x16x32_fp8_fp8(afr[kk], bf[kk], acc, 0, 0, 0);
  int tag = lane & 15, r4 = lane >> 4;
  if(tag < NTAG){
    float bb = fcb[tag];
    #pragma unroll
    for(int q = 0; q < 4; ++q){
      int b = grp * 16 + r4 * 4 + q;
      out[((size_t)b * Tt + t) * NTAG + tag] = acc[q] * (1.f / 4096.f) + bb;
    }
  }
}

// ---------------- CRF log-likelihood: one wave per batch row -----------------
__global__ __launch_bounds__(64) void crf_k(const int* __restrict__ inp,
    const int* __restrict__ labels, const float* __restrict__ trans,
    const float* __restrict__ logits, float* __restrict__ out){
  int b = blockIdx.x;
  int lane = threadIdx.x;
  int cnt = 0;
  for(int t = lane; t < Tt; t += 64) cnt += (inp[b * Tt + t] != 0) ? 1 : 0;
  #pragma unroll
  for(int off = 32; off >= 1; off >>= 1) cnt += __shfl_xor(cnt, off, 64);
  int len = cnt;
  float sc = 0.f;
  for(int t = lane; t < Tt; t += 64){
    if(t < len){
      int lab = labels[b * Tt + t];
      sc += logits[(size_t)(b * Tt + t) * NTAG + lab];
      if(t >= 1){
        int lp = labels[b * Tt + t - 1];
        sc += trans[lp * NTAG + lab];
      }
    }
  }
  #pragma unroll
  for(int off = 32; off >= 1; off >>= 1) sc += __shfl_xor(sc, off, 64);
  float Tc[NTAG];
  if(lane < NTAG){
    #pragma unroll
    for(int i = 0; i < NTAG; ++i) Tc[i] = trans[i * NTAG + lane];
  }
  float alpha = (lane < NTAG) ? logits[(size_t)(b * Tt) * NTAG + lane] : -3.0e38f;
  for(int t = 1; t < len; ++t){
    float av[NTAG];
    #pragma unroll
    for(int i = 0; i < NTAG; ++i) av[i] = __shfl(alpha, i, 64);
    if(lane < NTAG){
      float m = av[0] + Tc[0];
      #pragma unroll
      for(int i = 1; i < NTAG; ++i) m = fmaxf(m, av[i] + Tc[i]);
      float s = 0.f;
      #pragma unroll
      for(int i = 0; i < NTAG; ++i) s += __expf(av[i] + Tc[i] - m);
      alpha = __logf(s) + m + logits[(size_t)(b * Tt + t) * NTAG + lane];
    }
  }
  float av[NTAG];
  #pragma unroll
  for(int i = 0; i < NTAG; ++i) av[i] = __shfl(alpha, i, 64);
  float m = av[0];
  #pragma unroll
  for(int i = 1; i < NTAG; ++i) m = fmaxf(m, av[i]);
  float s = 0.f;
  #pragma unroll
  for(int i = 0; i < NTAG; ++i) s += __expf(av[i] - m);
  float ln = __logf(s) + m;
  if(lane == 0){
    out[(size_t)Bb * Tt * NTAG + b] = sc - ln;
    out[(size_t)Bb * Tt * NTAG + Bb + b] = (float)len;
  }
}

extern "C" void kernel_launch(void* const* d_in, const int* in_sizes, int n_in,
                              void* d_out, int out_size, void* d_ws, size_t ws_size,
                              hipStream_t stream) {
  const int*   inputs = (const int*)d_in[0];
  const int*   labels = (const int*)d_in[1];
  const float* emb    = (const float*)d_in[2];
  const float* Wf     = (const float*)d_in[3];
  const float* Uf     = (const float*)d_in[4];
  const float* bf_    = (const float*)d_in[5];
  const float* Wb     = (const float*)d_in[6];
  const float* Ub     = (const float*)d_in[7];
  const float* bb_    = (const float*)d_in[8];
  const float* fcW    = (const float*)d_in[9];
  const float* fcb    = (const float*)d_in[10];
  const float* trans  = (const float*)d_in[11];
  float* out = (float*)d_out;
  char* ws = (char*)d_ws;
  // workspace layout (bytes)
  u16*   xwpk  = (u16*)(ws + 0);              // 134217728
  u8*    hseq8 = (u8*) (ws + 134217728);      //  16777216
  u8*    Upk8  = (u8*) (ws + 150994944);      //    524288
  u16*   Wpk   = (u16*)(ws + 151519232);      //   1310720
  float* bperm = (float*)(ws + 152829952);    //      8192
  u8*    fcw8  = (u8*) (ws + 152838144);      //      8192
  u16*   xbf   = (u16*)(ws + 152846336);      //  20971520  (total ~174 MB)

  hipLaunchKernelGGL(prep_k, dim3(396 + 16384), dim3(256), 0, stream,
                     Wf, Wb, Uf, Ub, bf_, bb_, fcW, inputs, emb,
                     Wpk, Upk8, bperm, fcw8, xbf);
  hipLaunchKernelGGL(xw_gemm_k, dim3(16, 128), dim3(256), 0, stream, xbf, Wpk, bperm, xwpk);
  hipLaunchKernelGGL(lstm_rec_k, dim3(16), dim3(512), 0, stream, xwpk, Upk8, hseq8);
  hipLaunchKernelGGL(logits_k, dim3(512), dim3(256), 0, stream, hseq8, fcw8, fcb, out);
  hipLaunchKernelGGL(crf_k, dim3(128), dim3(64), 0, stream, inputs, labels, trans, out, out);
}

// Round 19
// 575.327 us; speedup vs baseline: 1.0334x; 1.0334x over previous
//
#include <hip/hip_runtime.h>
#include <hip/hip_bf16.h>
#include <stdint.h>

#define Bb 128
#define Tt 256
#define Ee 300
#define EP 320
#define Hh 256
#define G4 1024
#define NTAG 9

typedef __bf16 bf16x8 __attribute__((ext_vector_type(8)));
typedef float f32x4 __attribute__((ext_vector_type(4)));
typedef float f32x2 __attribute__((ext_vector_type(2)));
typedef int i32x8 __attribute__((ext_vector_type(8)));
typedef unsigned short u16;
typedef unsigned int u32;
typedef unsigned char u8;
typedef long i64;

union U4B { uint4 q; bf16x8 v; };

static __device__ __forceinline__ float bf2f(u32 u){
  union { float f; u32 u; } w; w.u = u << 16; return w.f;
}
static __device__ __forceinline__ u16 f2bf(float f){
  union { float f; u32 u; } w; w.f = f;
  u32 x = w.u;
  return (u16)((x + 0x7fffu + ((x >> 16) & 1u)) >> 16);
}
// permuted (dir-local) column -> original gate column. Permutation: wave w
// (c>>7) owns hidden units [32w,32w+32); within its 128 cols: 4 gates x 32.
static __device__ __forceinline__ int perm2orig(int c){
  int w = c >> 7, r = c & 127, g = r >> 5, jj = r & 31;
  return g * 256 + w * 32 + jj;
}
static __device__ __forceinline__ float frcp(float x){ return __builtin_amdgcn_rcpf(x); }
static __device__ __forceinline__ float fexp2(float x){
  float r; asm("v_exp_f32 %0, %1" : "=v"(r) : "v"(x)); return r;
}
static __device__ __forceinline__ f32x2 vexp2(f32x2 x){
  f32x2 r; r[0] = fexp2(x[0]); r[1] = fexp2(x[1]); return r;
}
static __device__ __forceinline__ f32x2 vrcp(f32x2 x){
  f32x2 r; r[0] = frcp(x[0]); r[1] = frcp(x[1]); return r;
}
static __device__ __forceinline__ f32x2 vfabs(f32x2 x){
  f32x2 r; r[0] = __builtin_fabsf(x[0]); r[1] = __builtin_fabsf(x[1]); return r;
}
static __device__ __forceinline__ f32x2 vminc(f32x2 x, float c){
  f32x2 r; r[0] = fminf(x[0], c); r[1] = fminf(x[1], c); return r;
}
static __device__ __forceinline__ f32x2 vcps(f32x2 m, f32x2 s){
  f32x2 r; r[0] = __builtin_copysignf(m[0], s[0]);
  r[1] = __builtin_copysignf(m[1], s[1]); return r;
}
static __device__ __forceinline__ void gl_lds16(const void* g, void* l){
  __builtin_amdgcn_global_load_lds((const __attribute__((address_space(1))) u32*)(g),
                                   (__attribute__((address_space(3))) u32*)(l), 16, 0, 0);
}

// ---------------- fused prep + gather ----------------------------------------
// blocks [0,320) W | [320,384) U | [384,392) b | [392,396) fcW | [396,...) gather
__global__ void prep_k(const float* __restrict__ Wf, const float* __restrict__ Wb,
                       const float* __restrict__ Uf, const float* __restrict__ Ub,
                       const float* __restrict__ bf_, const float* __restrict__ bb_,
                       const float* __restrict__ fcW, const int* __restrict__ inp,
                       const float* __restrict__ emb,
                       u16* __restrict__ Wpk, u8* __restrict__ Upk8,
                       float* __restrict__ bperm, u8* __restrict__ fcw8,
                       u16* __restrict__ xbf){
  int blk = blockIdx.x;
  if(blk < 320){
    int idx = blk * 256 + threadIdx.x;
    if(idx >= 128 * 10 * 64) return;
    int lane = idx & 63;
    int kk = (idx >> 6) % 10;
    int nt2 = idx / 640;
    int d = nt2 >> 6, ntd = nt2 & 63;
    int oc = perm2orig(ntd * 16 + (lane & 15));
    const float* W = d ? Wb : Wf;
    int k0 = kk * 32 + ((lane >> 4) << 3);
    u16 o[8];
    #pragma unroll
    for(int j = 0; j < 8; ++j){
      int k = k0 + j;
      o[j] = (k < Ee) ? f2bf(W[(size_t)k * G4 + oc]) : (u16)0;
    }
    uint4 q;
    q.x = o[0] | ((u32)o[1] << 16); q.y = o[2] | ((u32)o[3] << 16);
    q.z = o[4] | ((u32)o[5] << 16); q.w = o[6] | ((u32)o[7] << 16);
    *(uint4*)(Wpk + (size_t)idx * 8) = q;
  } else if(blk < 384){
    int idx = (blk - 320) * 256 + threadIdx.x;
    if(idx >= 2 * 64 * 2 * 64) return;
    int lane = idx & 63;
    int kh = (idx >> 6) & 1;
    int nt = (idx >> 7) & 63;
    int d = idx >> 13;
    int oc = perm2orig(nt * 16 + (lane & 15));
    const float* U = d ? Ub : Uf;
    int k0 = kh * 128 + (lane >> 4) * 32;
    u32 o[8];
    #pragma unroll
    for(int m = 0; m < 8; ++m){
      float v0 = U[(size_t)(k0 + 4 * m + 0) * G4 + oc] * 32.f;
      float v1 = U[(size_t)(k0 + 4 * m + 1) * G4 + oc] * 32.f;
      float v2 = U[(size_t)(k0 + 4 * m + 2) * G4 + oc] * 32.f;
      float v3 = U[(size_t)(k0 + 4 * m + 3) * G4 + oc] * 32.f;
      int pk = __builtin_amdgcn_cvt_pk_fp8_f32(v0, v1, 0, false);
      pk = __builtin_amdgcn_cvt_pk_fp8_f32(v2, v3, pk, true);
      o[m] = (u32)pk;
    }
    uint4* dst = (uint4*)(Upk8 + (size_t)idx * 32);
    dst[0] = (uint4){o[0], o[1], o[2], o[3]};
    dst[1] = (uint4){o[4], o[5], o[6], o[7]};
  } else if(blk < 392){
    int c = (blk - 384) * 256 + threadIdx.x;
    if(c >= 2048) return;
    const float* src = (c >> 10) ? bb_ : bf_;
    bperm[c] = src[perm2orig(c & 1023)];
  } else if(blk < 396){
    int idx = (blk - 392) * 256 + threadIdx.x;
    if(idx >= 1024) return;
    int lane = idx & 63, kk = idx >> 6;
    int col = lane & 15;
    int k0 = kk * 32 + ((lane >> 4) << 3);
    float v[8];
    #pragma unroll
    for(int j = 0; j < 8; ++j)
      v[j] = (col < NTAG) ? fcW[(size_t)(k0 + j) * NTAG + col] * 256.f : 0.f;
    int lo = __builtin_amdgcn_cvt_pk_fp8_f32(v[0], v[1], 0, false);
    lo = __builtin_amdgcn_cvt_pk_fp8_f32(v[2], v[3], lo, true);
    int hi = __builtin_amdgcn_cvt_pk_fp8_f32(v[4], v[5], 0, false);
    hi = __builtin_amdgcn_cvt_pk_fp8_f32(v[6], v[7], hi, true);
    uint2 q; q.x = (u32)lo; q.y = (u32)hi;
    *(uint2*)(fcw8 + (size_t)idx * 8) = q;
  } else {
    // gather: 2 rows per block; emb rows 16B-aligned (1200B stride)
    int row = (blk - 396) * 2 + (threadIdx.x >> 7);
    int j = threadIdx.x & 127;
    int t = row >> 7, b = row & 127;
    int tok = inp[b * Tt + t];
    u16* dst = xbf + (size_t)row * EP;
    if(j < 75){
      float4 v = *(const float4*)(emb + (size_t)tok * Ee + j * 4);
      u32 lo = f2bf(v.x) | ((u32)f2bf(v.y) << 16);
      u32 hi = f2bf(v.z) | ((u32)f2bf(v.w) << 16);
      *(uint2*)(dst + j * 4) = (uint2){lo, hi};
    } else if(j < 80){
      *(uint2*)(dst + j * 4) = (uint2){0u, 0u};
    }
  }
}

// ---------------- xW GEMM: 2 t-tiles per WG, B-frags reused ------------------
__global__ __launch_bounds__(256, 2) void xw_gemm_k(const u16* __restrict__ xbf,
    const u16* __restrict__ Wpk, const float* __restrict__ bperm,
    u16* __restrict__ xwpk){
  __shared__ uint4 At[2][512];       // 2 tiles x 128 rows x 64B, XOR-swizzled
  int t0 = blockIdx.y * 2, nblk = blockIdx.x;
  int tid = threadIdx.x, lane = tid & 63, w = tid >> 6;
  int mh = w >> 1, nh = w & 1;
  f32x4 acc[2][4][4];
  #pragma unroll
  for(int tt = 0; tt < 2; ++tt)
    #pragma unroll
    for(int i = 0; i < 4; ++i)
      #pragma unroll
      for(int j = 0; j < 4; ++j) acc[tt][i][j] = (f32x4){0.f, 0.f, 0.f, 0.f};
  for(int ks = 0; ks < 10; ++ks){
    __syncthreads();
    #pragma unroll
    for(int it = 0; it < 2; ++it){
      int row = it * 64 + w * 16 + (lane >> 2);
      int seg = (lane & 3) ^ (row & 3);
      gl_lds16(xbf + (size_t)(t0 * 128 + row) * EP + ks * 32 + seg * 8,
               &At[0][it * 256 + w * 64]);
      gl_lds16(xbf + (size_t)((t0 + 1) * 128 + row) * EP + ks * 32 + seg * 8,
               &At[1][it * 256 + w * 64]);
    }
    asm volatile("s_waitcnt vmcnt(0)" ::: "memory");
    __syncthreads();
    U4B bv[4];
    #pragma unroll
    for(int n = 0; n < 4; ++n){
      int ntg = nblk * 8 + nh * 4 + n;
      bv[n].q = *(const uint4*)(Wpk + ((size_t)(ntg * 10 + ks) * 64 + lane) * 8);
    }
    #pragma unroll
    for(int tt = 0; tt < 2; ++tt){
      U4B a[4];
      #pragma unroll
      for(int m = 0; m < 4; ++m){
        int row = (mh * 4 + m) * 16 + (lane & 15);
        a[m].q = At[tt][row * 4 + ((lane >> 4) ^ (row & 3))];
      }
      #pragma unroll
      for(int m = 0; m < 4; ++m)
        #pragma unroll
        for(int n = 0; n < 4; ++n)
          acc[tt][m][n] = __builtin_amdgcn_mfma_f32_16x16x32_bf16(a[m].v, bv[n].v, acc[tt][m][n], 0, 0, 0);
    }
  }
  #pragma unroll
  for(int tt = 0; tt < 2; ++tt){
    int t = t0 + tt;
    #pragma unroll
    for(int m = 0; m < 4; ++m){
      int grp = mh * 4 + m;
      #pragma unroll
      for(int n = 0; n < 4; ++n){
        int ntg = nblk * 8 + nh * 4 + n;
        int d = ntg >> 6, nd = ntg & 63;
        float bias = bperm[ntg * 16 + (lane & 15)];
        u16 h0 = f2bf((acc[tt][m][n][0] + bias) * 512.f), h1 = f2bf((acc[tt][m][n][1] + bias) * 512.f);
        u16 h2 = f2bf((acc[tt][m][n][2] + bias) * 512.f), h3 = f2bf((acc[tt][m][n][3] + bias) * 512.f);
        uint2 p; p.x = h0 | ((u32)h1 << 16); p.y = h2 | ((u32)h3 << 16);
        *(uint2*)(xwpk + ((((size_t)(d * 8 + grp) * Tt + t) * 64 + nd) * 64 + lane) * 4) = p;
      }
    }
  }
}

// ---------------- LSTM recurrence (R12-exact: LDS-staged xW, fp8 h path) -----
// 16 WGs x 512 thr (8 waves = 2/SIMD). U fp8 AGPR-pinned K=128 B-frags;
// v_mfma_f32_16x16x128_f8f6f4. Hf8 dbuf, ONE barrier/step. xW staged via
// gl_lds double-buffer, consumed after counted vmcnt(2).
__global__ __launch_bounds__(512, 2) void lstm_rec_k(const u16* __restrict__ xwpk,
    const u8* __restrict__ Upk8, u8* __restrict__ hseq8){
  __shared__ u32 Hf8[2][1024];       // 8KB  fp8 h transposed dbuf [unit*16+row]
  __shared__ uint2 Xw[2][4096];      // 64KB xW staging dbuf [w*512+n*64+lane]
  int bid = blockIdx.x;
  int d = bid >> 3, grp = bid & 7;
  int tid = threadIdx.x, lane = tid & 63, w = tid >> 6;   // w: 0..7
  int arow = lane & 15, r4 = lane >> 4;

  // preload U slice into K=128 B-fragments (fp8, 8nt x 2kh x 8 regs = 128),
  // pinned into AGPRs (no remat; MFMA reads B from AGPR natively)
  i32x8 Ureg[8][2];
  const u8* Ub8 = Upk8 + (size_t)d * 262144;
  #pragma unroll
  for(int n = 0; n < 8; ++n)
    #pragma unroll
    for(int kh = 0; kh < 2; ++kh)
      Ureg[n][kh] = *(const i32x8*)(Ub8 + (((size_t)(w * 8 + n) * 2 + kh) * 64 + lane) * 32);
  #pragma unroll
  for(int n = 0; n < 8; ++n)
    #pragma unroll
    for(int kh = 0; kh < 2; ++kh)
      asm volatile("" : "+a"(Ureg[n][kh]));

  Hf8[0][tid] = 0u; Hf8[0][tid + 512] = 0u;
  f32x2 cst2[2][2];
  #pragma unroll
  for(int a = 0; a < 2; ++a)
    #pragma unroll
    for(int p = 0; p < 2; ++p) cst2[a][p] = (f32x2){0.f, 0.f};
  const u16* xwb = xwpk + (size_t)(d * 8 + grp) * Tt * 16384;
  u8* hs_base = hseq8 + (size_t)(d * 8 + grp) * Tt * 4096;
  u32 hf8base = (u32)(uintptr_t)(&Hf8[0][0]);
  u32* hf8u = (u32*)(&Hf8[0][0]);

  const float c1s = -1.44269504f / 512.f;
  const f32x2 C1  = (f32x2){c1s, c1s};
  const f32x2 C2  = (f32x2){2.f * c1s, 2.f * c1s};
  const f32x2 C3  = (f32x2){-2.f * 1.44269504f, -2.f * 1.44269504f};
  const f32x2 ONE = (f32x2){1.f, 1.f};

  // prologue: stage xW(t0) into Xw[0], drain once
  {
    int t0 = d ? (Tt - 1) : 0;
    const u16* xwt0 = xwb + (size_t)t0 * 16384;
    #pragma unroll
    for(int j = 0; j < 4; ++j)
      gl_lds16(xwt0 + (w * 8 + 2 * j) * 256 + lane * 8, &Xw[0][w * 512 + 2 * j * 64]);
  }
  asm volatile("s_waitcnt vmcnt(0)" ::: "memory");
  __syncthreads();

  int cur = 0;
  for(int st = 0; st < Tt; ++st){
    int t = d ? (Tt - 1 - st) : st;
    int p = st & 1, c_ = p ^ 1;
    // A-fragments of h_{t-1} (K=128 x2): 8 tr_b8 reads from Hf8[p]
    union AFU { i64 dd[4]; i32x8 v; };
    AFU af0, af1;
    u32 av = hf8base + (u32)(p * 4096) + (u32)(r4 * 512 + arow * 8);
    asm volatile("ds_read_b64_tr_b8 %0, %1"             : "=v"(af0.dd[0]) : "v"(av));
    asm volatile("ds_read_b64_tr_b8 %0, %1 offset:128"  : "=v"(af0.dd[1]) : "v"(av));
    asm volatile("ds_read_b64_tr_b8 %0, %1 offset:256"  : "=v"(af0.dd[2]) : "v"(av));
    asm volatile("ds_read_b64_tr_b8 %0, %1 offset:384"  : "=v"(af0.dd[3]) : "v"(av));
    asm volatile("ds_read_b64_tr_b8 %0, %1 offset:2048" : "=v"(af1.dd[0]) : "v"(av));
    asm volatile("ds_read_b64_tr_b8 %0, %1 offset:2176" : "=v"(af1.dd[1]) : "v"(av));
    asm volatile("ds_read_b64_tr_b8 %0, %1 offset:2304" : "=v"(af1.dd[2]) : "v"(av));
    asm volatile("ds_read_b64_tr_b8 %0, %1 offset:2432" : "=v"(af1.dd[3]) : "v"(av));
    asm volatile("s_waitcnt lgkmcnt(0)" ::: "memory");   // afr data ready
    __builtin_amdgcn_sched_barrier(0);                   // rule 18: no MFMA hoist
    // xW(t) from LDS stage (counted: allow the 2 outstanding pk stores)
    asm volatile("s_waitcnt vmcnt(2)" ::: "memory");
    uint2 xw[8];
    #pragma unroll
    for(int n = 0; n < 8; ++n) xw[n] = Xw[cur][w * 512 + n * 64 + lane];
    // issue xW(t+1) stage into the other buffer (stays in flight)
    {
      int stn = (st + 1 < Tt) ? st + 1 : st;
      int tn = d ? (Tt - 1 - stn) : stn;
      const u16* xwtn = xwb + (size_t)tn * 16384;
      #pragma unroll
      for(int j = 0; j < 4; ++j)
        gl_lds16(xwtn + (w * 8 + 2 * j) * 256 + lane * 8, &Xw[cur ^ 1][w * 512 + 2 * j * 64]);
    }
    __builtin_amdgcn_sched_barrier(0);                   // pin loads before MFMA
    // acc init = 512*(xW+b)
    f32x4 acc[8];
    #pragma unroll
    for(int n = 0; n < 8; ++n){
      acc[n][0] = bf2f(xw[n].x & 0xffffu);
      acc[n][1] = bf2f(xw[n].x >> 16);
      acc[n][2] = bf2f(xw[n].y & 0xffffu);
      acc[n][3] = bf2f(xw[n].y >> 16);
    }
    // 16 K=128 MFMAs (fp8xfp8 via f8f6f4 default formats)
    #pragma unroll
    for(int n = 0; n < 8; ++n){
      asm volatile("v_mfma_f32_16x16x128_f8f6f4 %0, %1, %2, %0"
                   : "+v"(acc[n]) : "v"(af0.v), "a"(Ureg[n][0]));
      asm volatile("v_mfma_f32_16x16x128_f8f6f4 %0, %1, %2, %0"
                   : "+v"(acc[n]) : "v"(af1.v), "a"(Ureg[n][1]));
    }
    // gates: n {0,1}=i, {2,3}=f, {4,5}=g, {6,7}=o ; z = acc/512 (R12-exact)
    #pragma unroll
    for(int n1 = 0; n1 < 2; ++n1){
      f32x2 h16[2];
      #pragma unroll
      for(int pq = 0; pq < 2; ++pq){
        f32x2 ai = (f32x2){acc[0 + n1][2 * pq], acc[0 + n1][2 * pq + 1]};
        f32x2 af = (f32x2){acc[2 + n1][2 * pq], acc[2 + n1][2 * pq + 1]};
        f32x2 ag = (f32x2){acc[4 + n1][2 * pq], acc[4 + n1][2 * pq + 1]};
        f32x2 ao = (f32x2){acc[6 + n1][2 * pq], acc[6 + n1][2 * pq + 1]};
        f32x2 ei = vexp2(ai * C1);
        f32x2 ef = vexp2(af * C1);
        f32x2 eo = vexp2(ao * C1);
        f32x2 eg = vexp2(vminc(vfabs(ag), 10240.f) * C2);
        f32x2 ig = vcps(ONE - eg, ag) * vrcp((ONE + ei) * (ONE + eg));
        f32x2 fs = vrcp(ONE + ef);
        f32x2 cc = fs * cst2[n1][pq] + ig;
        cst2[n1][pq] = cc;
        f32x2 ec = vexp2(vminc(vfabs(cc), 20.f) * C3);
        f32x2 hh = vcps(ONE - ec, cc) * vrcp((ONE + eo) * (ONE + ec));
        h16[pq] = hh * (f32x2){16.f, 16.f};
      }
      int pk = __builtin_amdgcn_cvt_pk_fp8_f32(h16[0][0], h16[0][1], 0, false);
      pk = __builtin_amdgcn_cvt_pk_fp8_f32(h16[1][0], h16[1][1], pk, true);
      int unit = w * 32 + n1 * 16 + arow;
      hf8u[c_ * 1024 + unit * 4 + r4] = (u32)pk;
      *(u32*)(hs_base + (size_t)t * 4096 + unit * 16 + r4 * 4) = (u32)pk;
    }
    asm volatile("s_waitcnt lgkmcnt(0)" ::: "memory");   // h_t LDS writes done
    __builtin_amdgcn_s_barrier();                        // the ONE barrier
    cur ^= 1;
  }
}

// ---------------- logits: one wave per (grp,t), tr_b8 + fp8 MFMA -------------
__global__ __launch_bounds__(256) void logits_k(const u8* __restrict__ hseq8,
    const u8* __restrict__ fcw8, const float* __restrict__ fcb,
    float* __restrict__ out){
  __shared__ u8 Ht[4][8192];
  int widx = threadIdx.x >> 6, lane = threadIdx.x & 63;
  int wid = blockIdx.x * 4 + widx;
  int grp = wid >> 8, t = wid & 255;
  i64 bf[16];
  #pragma unroll
  for(int kk = 0; kk < 16; ++kk)
    bf[kk] = *(const i64*)(fcw8 + ((size_t)kk * 64 + lane) * 8);
  const u8* hf = hseq8 + ((size_t)(0 * 8 + grp) * Tt + t) * 4096;
  const u8* hb = hseq8 + ((size_t)(1 * 8 + grp) * Tt + t) * 4096;
  #pragma unroll
  for(int j = 0; j < 4; ++j){
    gl_lds16(hf + j * 1024 + lane * 16, &Ht[widx][j * 1024]);
    gl_lds16(hb + j * 1024 + lane * 16, &Ht[widx][4096 + j * 1024]);
  }
  asm volatile("s_waitcnt vmcnt(0)" ::: "memory");
  __builtin_amdgcn_sched_barrier(0);
  u32 base = (u32)(uintptr_t)(&Ht[widx][0]) + lane * 8;
  i64 afr[16];
  #pragma unroll
  for(int kk = 0; kk < 16; ++kk){
    u32 a = base + kk * 512;
    asm volatile("ds_read_b64_tr_b8 %0, %1" : "=v"(afr[kk]) : "v"(a));
  }
  asm volatile("s_waitcnt lgkmcnt(0)" ::: "memory");
  __builtin_amdgcn_sched_barrier(0);
  f32x4 acc = (f32x4){0.f, 0.f, 0.f, 0.f};
  #pragma unroll
  for(int kk = 0; kk < 16; ++kk)
    acc = __builtin_amdgcn_mfma_f32_16x16x32_fp8_fp8(afr[kk], bf[kk], acc, 0, 0, 0);
  int tag = lane & 15, r4 = lane >> 4;
  if(tag < NTAG){
    float bb = fcb[tag];
    #pragma unroll
    for(int q = 0; q < 4; ++q){
      int b = grp * 16 + r4 * 4 + q;
      out[((size_t)b * Tt + t) * NTAG + tag] = acc[q] * (1.f / 4096.f) + bb;
    }
  }
}

// ---------------- CRF log-likelihood: one wave per batch row -----------------
__global__ __launch_bounds__(64) void crf_k(const int* __restrict__ inp,
    const int* __restrict__ labels, const float* __restrict__ trans,
    const float* __restrict__ logits, float* __restrict__ out){
  int b = blockIdx.x;
  int lane = threadIdx.x;
  int cnt = 0;
  for(int t = lane; t < Tt; t += 64) cnt += (inp[b * Tt + t] != 0) ? 1 : 0;
  #pragma unroll
  for(int off = 32; off >= 1; off >>= 1) cnt += __shfl_xor(cnt, off, 64);
  int len = cnt;
  float sc = 0.f;
  for(int t = lane; t < Tt; t += 64){
    if(t < len){
      int lab = labels[b * Tt + t];
      sc += logits[(size_t)(b * Tt + t) * NTAG + lab];
      if(t >= 1){
        int lp = labels[b * Tt + t - 1];
        sc += trans[lp * NTAG + lab];
      }
    }
  }
  #pragma unroll
  for(int off = 32; off >= 1; off >>= 1) sc += __shfl_xor(sc, off, 64);
  float Tc[NTAG];
  if(lane < NTAG){
    #pragma unroll
    for(int i = 0; i < NTAG; ++i) Tc[i] = trans[i * NTAG + lane];
  }
  float alpha = (lane < NTAG) ? logits[(size_t)(b * Tt) * NTAG + lane] : -3.0e38f;
  for(int t = 1; t < len; ++t){
    float av[NTAG];
    #pragma unroll
    for(int i = 0; i < NTAG; ++i) av[i] = __shfl(alpha, i, 64);
    if(lane < NTAG){
      float m = av[0] + Tc[0];
      #pragma unroll
      for(int i = 1; i < NTAG; ++i) m = fmaxf(m, av[i] + Tc[i]);
      float s = 0.f;
      #pragma unroll
      for(int i = 0; i < NTAG; ++i) s += __expf(av[i] + Tc[i] - m);
      alpha = __logf(s) + m + logits[(size_t)(b * Tt + t) * NTAG + lane];
    }
  }
  float av[NTAG];
  #pragma unroll
  for(int i = 0; i < NTAG; ++i) av[i] = __shfl(alpha, i, 64);
  float m = av[0];
  #pragma unroll
  for(int i = 1; i < NTAG; ++i) m = fmaxf(m, av[i]);
  float s = 0.f;
  #pragma unroll
  for(int i = 0; i < NTAG; ++i) s += __expf(av[i] - m);
  float ln = __logf(s) + m;
  if(lane == 0){
    out[(size_t)Bb * Tt * NTAG + b] = sc - ln;
    out[(size_t)Bb * Tt * NTAG + Bb + b] = (float)len;
  }
}

extern "C" void kernel_launch(void* const* d_in, const int* in_sizes, int n_in,
                              void* d_out, int out_size, void* d_ws, size_t ws_size,
                              hipStream_t stream) {
  const int*   inputs = (const int*)d_in[0];
  const int*   labels = (const int*)d_in[1];
  const float* emb    = (const float*)d_in[2];
  const float* Wf     = (const float*)d_in[3];
  const float* Uf     = (const float*)d_in[4];
  const float* bf_    = (const float*)d_in[5];
  const float* Wb     = (const float*)d_in[6];
  const float* Ub     = (const float*)d_in[7];
  const float* bb_    = (const float*)d_in[8];
  const float* fcW    = (const float*)d_in[9];
  const float* fcb    = (const float*)d_in[10];
  const float* trans  = (const float*)d_in[11];
  float* out = (float*)d_out;
  char* ws = (char*)d_ws;
  // workspace layout (bytes)
  u16*   xwpk  = (u16*)(ws + 0);              // 134217728
  u8*    hseq8 = (u8*) (ws + 134217728);      //  16777216
  u8*    Upk8  = (u8*) (ws + 150994944);      //    524288
  u16*   Wpk   = (u16*)(ws + 151519232);      //   1310720
  float* bperm = (float*)(ws + 152829952);    //      8192
  u8*    fcw8  = (u8*) (ws + 152838144);      //      8192
  u16*   xbf   = (u16*)(ws + 152846336);      //  20971520  (total ~174 MB)

  hipLaunchKernelGGL(prep_k, dim3(396 + 16384), dim3(256), 0, stream,
                     Wf, Wb, Uf, Ub, bf_, bb_, fcW, inputs, emb,
                     Wpk, Upk8, bperm, fcw8, xbf);
  hipLaunchKernelGGL(xw_gemm_k, dim3(16, 128), dim3(256), 0, stream, xbf, Wpk, bperm, xwpk);
  hipLaunchKernelGGL(lstm_rec_k, dim3(16), dim3(512), 0, stream, xwpk, Upk8, hseq8);
  hipLaunchKernelGGL(logits_k, dim3(512), dim3(256), 0, stream, hseq8, fcw8, fcb, out);
  hipLaunchKernelGGL(crf_k, dim3(128), dim3(64), 0, stream, inputs, labels, trans, out, out);
}